// Round 9
// baseline (423.897 us; speedup 1.0000x reference)
//
#include <hip/hip_runtime.h>

using short8   = __attribute__((ext_vector_type(8))) short;
using f32x4    = __attribute__((ext_vector_type(4))) float;
using ushort4v = __attribute__((ext_vector_type(4))) unsigned short;

#define BN_EPS 1e-5f
// log2(e)/sqrt(32): folded into q projection so softmax uses native exp2
#define ATT_SCALE_LOG2E 0.2550348347988049f

__device__ __forceinline__ unsigned short f2bf(float f) {
    union { float f; unsigned u; } v; v.f = f;
    return (unsigned short)((v.u + 0x7FFFu + ((v.u >> 16) & 1u)) >> 16);  // RNE
}

// pack two f32 -> two bf16 (round-half-up): a in low 16, b in high 16
__device__ __forceinline__ unsigned pack2bf(float a, float b) {
    union { float f; unsigned u; } ua, ub; ua.f = a; ub.f = b;
    return __builtin_amdgcn_perm(ub.u + 0x8000u, ua.u + 0x8000u, 0x07060302u);
}

// async global->LDS, 16B per lane. gp: per-lane global src. lp: wave-uniform
// LDS base (HW adds lane*16).
__device__ __forceinline__ void glds16(const void* gp, void* lp) {
    __builtin_amdgcn_global_load_lds(
        (const __attribute__((address_space(1))) unsigned*)gp,
        (__attribute__((address_space(3))) unsigned*)lp, 16, 0, 0);
}

// ---------------------------------------------------------------------------
// Kernel 0: weights -> bf16; fold conv-bias + BN into per-row (scale, offset).
// Rows: 0-31 q, 32-63 k, 64-319 v.
// ---------------------------------------------------------------------------
__global__ void prep_kernel(
    const float* __restrict__ qw, const float* __restrict__ qb,
    const float* __restrict__ qg, const float* __restrict__ qbe,
    const float* __restrict__ qm, const float* __restrict__ qv,
    const float* __restrict__ kw, const float* __restrict__ kb,
    const float* __restrict__ kg, const float* __restrict__ kbe,
    const float* __restrict__ km, const float* __restrict__ kvv,
    const float* __restrict__ vw, const float* __restrict__ vb,
    const float* __restrict__ vg, const float* __restrict__ vbe,
    const float* __restrict__ vm, const float* __restrict__ vv,
    unsigned short* __restrict__ wq, float* __restrict__ scale,
    float* __restrict__ off)
{
    int r = blockIdx.x;      // 0..319
    int t = threadIdx.x;     // 0..63
    const float *wsrc, *g, *be, *mn, *vr, *bi;
    int rl;
    if (r < 32)      { rl = r;      wsrc = qw; g = qg; be = qbe; mn = qm; vr = qv;  bi = qb; }
    else if (r < 64) { rl = r - 32; wsrc = kw; g = kg; be = kbe; mn = km; vr = kvv; bi = kb; }
    else             { rl = r - 64; wsrc = vw; g = vg; be = vbe; mn = vm; vr = vv;  bi = vb; }

    float4 w4 = *(const float4*)(wsrc + rl * 256 + t * 4);
    ushort4v o;
    o.x = f2bf(w4.x); o.y = f2bf(w4.y); o.z = f2bf(w4.z); o.w = f2bf(w4.w);
    *(ushort4v*)(wq + r * 256 + t * 4) = o;

    if (t == 0) {
        float inv = g[rl] * rsqrtf(vr[rl] + BN_EPS);
        float ofv = bi[rl] * inv + be[rl] - mn[rl] * inv;
        float s = (r < 32) ? ATT_SCALE_LOG2E : 1.0f;
        scale[r] = inv * s;
        off[r]   = ofv * s;
    }
}

// ---------------------------------------------------------------------------
// Kernel 1: projections (r2 structure). bx>>8 = g: 0: q(x1), 1: k(x2),
// 2: v ALL 256 rows (x2). Grid 768. q_t/k_t: [b][n][32] bf16.
// v_ws: PAIR-INTERLEAVED tile-blocked layout for flash's fused-PV b128 reads:
//   [b][tp=0..31][c=0..255][16 granules x 16B], granule g (keys 4g..4g+3 of
//   the 64-key tile) = [tileA=2tp 8B | tileB=2tp+1 8B], granule slot
//   XOR-swizzled ONCE here: slot = (g&8) | ((g&7) ^ (c&7)). Flash DMAs this
//   image VERBATIM into linear LDS and applies the same swizzle on READ.
// ---------------------------------------------------------------------------
#define XT_PITCH 264

__global__ __launch_bounds__(256, 4) void proj_kernel(
    const float* __restrict__ x1, const float* __restrict__ x2,
    const unsigned short* __restrict__ wq,
    const float* __restrict__ scale, const float* __restrict__ off,
    unsigned short* __restrict__ q_t, unsigned short* __restrict__ k_t,
    unsigned short* __restrict__ v_ws)
{
    __shared__ __align__(16) unsigned short Xt[64 * XT_PITCH];   // 33792 B
    int bx = blockIdx.x;
    int g  = bx >> 8;        // 0,1,2
    int t2 = bx & 255;
    int nt = t2 & 63;
    int b  = t2 >> 6;
    int n0 = nt * 64;
    int tid = threadIdx.x;
    int wv = tid >> 6, lane = tid & 63;
    int m16 = lane & 15, qd = lane >> 4;

    const float* xb = ((g == 0) ? x1 : x2) + (size_t)b * 256 * 4096 + n0 + lane;

    // octet-gather transpose: n = lane, channels 8*o..8*o+7, o = wv*8+i
    #pragma unroll 2
    for (int i = 0; i < 8; ++i) {
        int o = wv * 8 + i;                       // 0..31
        const float* src = xb + (size_t)(o * 8) * 4096;
        uint4 dw;
        dw.x = pack2bf(src[0],                src[(size_t)1 * 4096]);
        dw.y = pack2bf(src[(size_t)2 * 4096], src[(size_t)3 * 4096]);
        dw.z = pack2bf(src[(size_t)4 * 4096], src[(size_t)5 * 4096]);
        dw.w = pack2bf(src[(size_t)6 * 4096], src[(size_t)7 * 4096]);
        *(uint4*)&Xt[lane * XT_PITCH + o * 8] = dw;
    }
    __syncthreads();

    f32x4 zero4 = {0.f, 0.f, 0.f, 0.f};

    if (g < 2) {
        int rb = g * 32;
        f32x4 acc0 = zero4, acc1 = zero4;
        #pragma unroll 2
        for (int s = 0; s < 8; ++s) {
            short8 w0 = *(const short8*)(wq + (size_t)(rb +      m16) * 256 + s * 32 + qd * 8);
            short8 w1 = *(const short8*)(wq + (size_t)(rb + 16 + m16) * 256 + s * 32 + qd * 8);
            short8 xf = *(const short8*)&Xt[(16 * wv + m16) * XT_PITCH + s * 32 + qd * 8];
            acc0 = __builtin_amdgcn_mfma_f32_16x16x32_bf16(w0, xf, acc0, 0, 0, 0);
            acc1 = __builtin_amdgcn_mfma_f32_16x16x32_bf16(w1, xf, acc1, 0, 0, 0);
        }
        unsigned short* dst = (g == 0) ? q_t : k_t;
        int ncol = n0 + 16 * wv + m16;
        #pragma unroll
        for (int tm = 0; tm < 2; ++tm) {
            f32x4 acc = tm ? acc1 : acc0;
            int r0 = 16 * tm + 4 * qd;
            float4 sc = *(const float4*)(scale + rb + r0);
            float4 of = *(const float4*)(off   + rb + r0);
            ushort4v o;
            o.x = f2bf(acc.x * sc.x + of.x);
            o.y = f2bf(acc.y * sc.y + of.y);
            o.z = f2bf(acc.z * sc.z + of.z);
            o.w = f2bf(acc.w * sc.w + of.w);
            *(ushort4v*)(dst + ((size_t)b * 4096 + ncol) * 32 + r0) = o;
        }
    } else {
        // v: all 256 rows from one x2 transpose
        f32x4 acc[4][4];
        #pragma unroll
        for (int rr = 0; rr < 4; ++rr)
            #pragma unroll
            for (int tm = 0; tm < 4; ++tm) acc[rr][tm] = zero4;
        #pragma unroll 1
        for (int s = 0; s < 8; ++s) {
            short8 xf[4];
            #pragma unroll
            for (int tm = 0; tm < 4; ++tm)
                xf[tm] = *(const short8*)&Xt[(16 * tm + m16) * XT_PITCH + s * 32 + qd * 8];
            #pragma unroll
            for (int rr = 0; rr < 4; ++rr) {
                short8 wf = *(const short8*)(wq + (size_t)(64 + rr * 64 + 16 * wv + m16) * 256 + s * 32 + qd * 8);
                #pragma unroll
                for (int tm = 0; tm < 4; ++tm)
                    acc[rr][tm] = __builtin_amdgcn_mfma_f32_16x16x32_bf16(xf[tm], wf, acc[rr][tm], 0, 0, 0);
            }
        }
        // pair-interleaved swizzled store
        unsigned short* vt = v_ws + ((size_t)b * 32 + (nt >> 1)) * 32768;
        int h = nt & 1;
        #pragma unroll
        for (int rr = 0; rr < 4; ++rr) {
            int c = rr * 64 + 16 * wv + m16;
            float sc = scale[64 + c], of = off[64 + c];
            #pragma unroll
            for (int tm = 0; tm < 4; ++tm) {
                int gg = 4 * tm + qd;                           // granule 0..15
                int gs = (gg & 8) | ((gg & 7) ^ (c & 7));       // swizzled slot
                ushort4v o;
                o.x = f2bf(acc[rr][tm].x * sc + of);
                o.y = f2bf(acc[rr][tm].y * sc + of);
                o.z = f2bf(acc[rr][tm].z * sc + of);
                o.w = f2bf(acc[rr][tm].w * sc + of);
                *(ushort4v*)(vt + c * 128 + gs * 8 + h * 4) = o;
            }
        }
    }
}

// ---------------------------------------------------------------------------
// Kernel 2: flash attention v8 — v7b + CROSS-EPOCH SOFTMAX PIPELINE with
// counted vmcnt (T3/T4). P is wave-local (v7b's two-tile fusion), so the
// softmax of pair ep+1 can run entirely under PV(ep) with no sync:
//   epoch ep: B1 = vmcnt(8)+barrier  [DMA(ep) + K(ep+1) retired; DMA(ep+1)
//             stays in flight — never drain to 0 in the loop];
//             ds_read Vf(ep); issue QK(ep+1) MFMAs;
//             B2 = lgkmcnt(0)+barrier [all waves hold Vf(ep) in regs ->
//             buf[ep&1] clobberable];
//             load K(ep+2); DMA V(ep+2) -> buf[ep&1];
//             exp2/pack(ep+1) -> ap_next (VALU, overlaps PV's MFMAs);
//             PV(ep) 32 MFMAs with ap_cur.
// ap/K ping-pong via named register sets (2x-unrolled loop, static indices).
// vmcnt invariant (verified per-epoch): at B1(ep) retiring all but newest 8
// vmem ops == exactly {DMA(ep), K(ep+1)} done, {DMA(ep+1)} in flight.
// Last epoch peeled with vmcnt(0). Epilogue unchanged from v7b.
// ---------------------------------------------------------------------------
__global__ __launch_bounds__(256, 2) void flash_kernel(
    const unsigned short* __restrict__ q_t, const unsigned short* __restrict__ k_t,
    const unsigned short* __restrict__ v_ws, float* __restrict__ out)
{
    __shared__ __align__(16) unsigned char Vb[2][32768];   // 64 KB V pair dbuf / scratch
    __shared__ __align__(16) float Lsh[256];               // 1 KB

    int bx = blockIdx.x;                   // 512 blocks
    int cg = (bx >> 2) & 1;
    int b  = bx & 3;
    int qg = bx >> 3;                      // 0..63
    int q0 = qg * 64;
    int cb = cg * 128;

    int tid = threadIdx.x;
    int wv  = tid >> 6, lane = tid & 63;   // wv = key-slice owner
    int m16 = lane & 15, qd = lane >> 4;

    // ---- V DMA: verbatim copy of the (pre-swizzled) global image ----
    const char* vpb = (const char*)v_ws + (size_t)b * 2097152 + (size_t)cb * 256;
    int vgo[8], vl[8];
    #pragma unroll
    for (int u = 0; u < 8; ++u) {
        int i = (wv * 8 + u) * 64 + lane;          // 16B unit 0..2047
        vgo[u] = i * 16;                           // PLAIN linear source
        vl[u]  = (wv * 8 + u) * 1024;              // wave-uniform LDS base
    }
    // ---- V read offset: granule gw of row c_loc, swizzle applied on READ ----
    int gw = wv * 4 + qd;
    int gs = (gw & 8) | ((gw & 7) ^ (m16 & 7));
    int vro[8];
    #pragma unroll
    for (int ct = 0; ct < 8; ++ct) vro[ct] = (ct * 16 + m16) * 256 + gs * 16;

    // ---- K global base (wave's 16 rows, contiguous -> 1KB coalesced) ----
    const unsigned short* kbase = k_t + ((size_t)b * 4096 + wv * 16 + m16) * 32 + qd * 8;

    // ---- persistent Q fragments (all 4 q-tiles) ----
    const unsigned short* qb = q_t + ((size_t)b * 4096 + q0) * 32;
    short8 Qf[4];
    #pragma unroll
    for (int qt = 0; qt < 4; ++qt)
        Qf[qt] = *(const short8*)(qb + (size_t)(qt * 16 + m16) * 32 + qd * 8);

    f32x4 zero4 = {0.f, 0.f, 0.f, 0.f};
    f32x4 acc[4][8];
    #pragma unroll
    for (int qt = 0; qt < 4; ++qt)
        #pragma unroll
        for (int ct = 0; ct < 8; ++ct) acc[qt][ct] = zero4;
    float lsum[4] = {0.f, 0.f, 0.f, 0.f};

    // ---- prologue: K(0),K(1) loads FIRST, then DMA(0),DMA(1) ----
    short8 KA0 = *(const short8*)kbase;              // K pair 0
    short8 KA1 = *(const short8*)(kbase + 2048);
    short8 KB0 = *(const short8*)(kbase + 4096);     // K pair 1
    short8 KB1 = *(const short8*)(kbase + 4096 + 2048);
    #pragma unroll
    for (int u = 0; u < 8; ++u) glds16(vpb + vgo[u], (char*)Vb + vl[u]);
    #pragma unroll
    for (int u = 0; u < 8; ++u) glds16(vpb + 65536 + vgo[u], (char*)Vb[1] + vl[u]);
    // K loads retired (16 glds16 may remain outstanding)
    asm volatile("s_waitcnt vmcnt(16)" ::: "memory");

    // QK(0) + exp2 -> apA (pair 0)
    short8 apA[4], apB[4];
    #pragma unroll
    for (int qt = 0; qt < 4; ++qt) {
        f32x4 SA = __builtin_amdgcn_mfma_f32_16x16x32_bf16(KA0, Qf[qt], zero4, 0, 0, 0);
        f32x4 SB = __builtin_amdgcn_mfma_f32_16x16x32_bf16(KA1, Qf[qt], zero4, 0, 0, 0);
        float a0 = __builtin_amdgcn_exp2f(SA.x), a1 = __builtin_amdgcn_exp2f(SA.y);
        float a2 = __builtin_amdgcn_exp2f(SA.z), a3 = __builtin_amdgcn_exp2f(SA.w);
        float b0 = __builtin_amdgcn_exp2f(SB.x), b1 = __builtin_amdgcn_exp2f(SB.y);
        float b2 = __builtin_amdgcn_exp2f(SB.z), b3 = __builtin_amdgcn_exp2f(SB.w);
        lsum[qt] += ((a0 + a1) + (a2 + a3)) + ((b0 + b1) + (b2 + b3));
        union { uint4 u; short8 s; } w;
        w.u.x = pack2bf(a0, a1); w.u.y = pack2bf(a2, a3);
        w.u.z = pack2bf(b0, b1); w.u.w = pack2bf(b2, b3);
        apA[qt] = w.s;
    }

    // epoch body: PV(ep) w/ apC+Vf(ep); QK(ep+1) w/ Ku -> apN; prefetch ep+2
    auto body = [&](short8 (&apC)[4], short8 (&apN)[4],
                    const short8& Ku0, const short8& Ku1,
                    short8& Kl0, short8& Kl1, int ep) {
        // B1: DMA(ep) + K(ep+1) retired; DMA(ep+1) (newest 8) in flight
        asm volatile("s_waitcnt vmcnt(8)\n\ts_barrier" ::: "memory");
        char* Vcur = (char*)Vb + (size_t)(ep & 1) * 32768;

        short8 Vf[8];
        #pragma unroll
        for (int ct = 0; ct < 8; ++ct)
            Vf[ct] = *(const short8*)(Vcur + vro[ct]);

        // QK(ep+1): issue early on the MFMA pipe
        f32x4 SA[4], SB[4];
        bool doQK = (ep < 31);
        if (doQK) {
            #pragma unroll
            for (int qt = 0; qt < 4; ++qt) {
                SA[qt] = __builtin_amdgcn_mfma_f32_16x16x32_bf16(Ku0, Qf[qt], zero4, 0, 0, 0);
                SB[qt] = __builtin_amdgcn_mfma_f32_16x16x32_bf16(Ku1, Qf[qt], zero4, 0, 0, 0);
            }
        }

        // B2: all waves hold Vf(ep) in regs -> buf[ep&1] safe to clobber
        asm volatile("s_waitcnt lgkmcnt(0)\n\ts_barrier" ::: "memory");

        if (ep < 30) {   // prefetch pair ep+2: K loads FIRST, then DMA
            const unsigned short* ks = kbase + (size_t)(ep + 2) * 4096;
            Kl0 = *(const short8*)ks;
            Kl1 = *(const short8*)(ks + 2048);
            const char* vs = vpb + (size_t)(ep + 2) * 65536;
            #pragma unroll
            for (int u = 0; u < 8; ++u) glds16(vs + vgo[u], Vcur + vl[u]);
        }

        // exp2/pack(ep+1) -> apN : VALU work overlapping PV's MFMAs
        if (doQK) {
            #pragma unroll
            for (int qt = 0; qt < 4; ++qt) {
                float a0 = __builtin_amdgcn_exp2f(SA[qt].x), a1 = __builtin_amdgcn_exp2f(SA[qt].y);
                float a2 = __builtin_amdgcn_exp2f(SA[qt].z), a3 = __builtin_amdgcn_exp2f(SA[qt].w);
                float b0 = __builtin_amdgcn_exp2f(SB[qt].x), b1 = __builtin_amdgcn_exp2f(SB[qt].y);
                float b2 = __builtin_amdgcn_exp2f(SB[qt].z), b3 = __builtin_amdgcn_exp2f(SB[qt].w);
                lsum[qt] += ((a0 + a1) + (a2 + a3)) + ((b0 + b1) + (b2 + b3));
                union { uint4 u; short8 s; } w;
                w.u.x = pack2bf(a0, a1); w.u.y = pack2bf(a2, a3);
                w.u.z = pack2bf(b0, b1); w.u.w = pack2bf(b2, b3);
                apN[qt] = w.s;
            }
        }

        // PV(ep): 32 MFMAs with the PREVIOUS epoch's ap
        __builtin_amdgcn_s_setprio(1);
        #pragma unroll
        for (int ct = 0; ct < 8; ++ct) {
            #pragma unroll
            for (int qt = 0; qt < 4; ++qt)
                acc[qt][ct] = __builtin_amdgcn_mfma_f32_16x16x32_bf16(apC[qt], Vf[ct], acc[qt][ct], 0, 0, 0);
        }
        __builtin_amdgcn_s_setprio(0);
    };

    #pragma unroll 1
    for (int ep = 0; ep < 30; ep += 2) {
        body(apA, apB, KB0, KB1, KA0, KA1, ep);        // even: PV(ep), QK(ep+1)
        body(apB, apA, KA0, KA1, KB0, KB1, ep + 1);    // odd
    }
    body(apA, apB, KB0, KB1, KA0, KA1, 30);            // PV(30), QK(31)->apB

    // ---- peeled last epoch 31: full drain, no QK/prefetch ----
    {
        asm volatile("s_waitcnt vmcnt(0)\n\ts_barrier" ::: "memory");
        char* Vcur = (char*)Vb + 32768;
        short8 Vf[8];
        #pragma unroll
        for (int ct = 0; ct < 8; ++ct)
            Vf[ct] = *(const short8*)(Vcur + vro[ct]);
        __builtin_amdgcn_s_setprio(1);
        #pragma unroll
        for (int ct = 0; ct < 8; ++ct) {
            #pragma unroll
            for (int qt = 0; qt < 4; ++qt)
                acc[qt][ct] = __builtin_amdgcn_mfma_f32_16x16x32_bf16(apB[qt], Vf[ct], acc[qt][ct], 0, 0, 0);
        }
        __builtin_amdgcn_s_setprio(0);
    }

    // ---- denominators: reduce over qd in-wave; publish per key-slice ----
    #pragma unroll
    for (int qt = 0; qt < 4; ++qt) {
        float l = lsum[qt];
        l += __shfl_xor(l, 16);
        l += __shfl_xor(l, 32);
        if (lane < 16) Lsh[wv * 64 + qt * 16 + lane] = l;
    }

    // ---- O-combine over key-slices: 2-round conflict-free LDS tree ----
    char* X = (char*)Vb;   // 64 KB scratch (V bufs dead)
    asm volatile("s_waitcnt vmcnt(0) lgkmcnt(0)\n\ts_barrier" ::: "memory");
    if (wv >= 2) {
        char* dst = X + (size_t)(wv - 2) * 32768;
        #pragma unroll
        for (int qt = 0; qt < 4; ++qt)
            #pragma unroll
            for (int ct = 0; ct < 8; ++ct)
                *(f32x4*)(dst + (qt * 8 + ct) * 1024 + lane * 16) = acc[qt][ct];
    }
    asm volatile("s_waitcnt lgkmcnt(0)\n\ts_barrier" ::: "memory");
    if (wv < 2) {
        const char* src = X + (size_t)wv * 32768;
        #pragma unroll
        for (int qt = 0; qt < 4; ++qt)
            #pragma unroll
            for (int ct = 0; ct < 8; ++ct)
                acc[qt][ct] += *(const f32x4*)(src + (qt * 8 + ct) * 1024 + lane * 16);
    }
    asm volatile("s_waitcnt lgkmcnt(0)\n\ts_barrier" ::: "memory");
    if (wv == 1) {
        char* dst = X + 32768;
        #pragma unroll
        for (int qt = 0; qt < 4; ++qt)
            #pragma unroll
            for (int ct = 0; ct < 8; ++ct)
                *(f32x4*)(dst + (qt * 8 + ct) * 1024 + lane * 16) = acc[qt][ct];
    }
    asm volatile("s_waitcnt lgkmcnt(0)\n\ts_barrier" ::: "memory");
    if (wv == 0) {
        const char* src = X + 32768;
        #pragma unroll
        for (int qt = 0; qt < 4; ++qt)
            #pragma unroll
            for (int ct = 0; ct < 8; ++ct)
                acc[qt][ct] += *(const f32x4*)(src + (qt * 8 + ct) * 1024 + lane * 16);

        #pragma unroll
        for (int qt = 0; qt < 4; ++qt) {
            f32x4 s4 = *(const f32x4*)&Lsh[qt * 16 + qd * 4];
            s4 += *(const f32x4*)&Lsh[64  + qt * 16 + qd * 4];
            s4 += *(const f32x4*)&Lsh[128 + qt * 16 + qd * 4];
            s4 += *(const f32x4*)&Lsh[192 + qt * 16 + qd * 4];
            f32x4 inv4;
            inv4.x = __builtin_amdgcn_rcpf(s4.x);
            inv4.y = __builtin_amdgcn_rcpf(s4.y);
            inv4.z = __builtin_amdgcn_rcpf(s4.z);
            inv4.w = __builtin_amdgcn_rcpf(s4.w);
            #pragma unroll
            for (int ct = 0; ct < 8; ++ct) {
                // acc: col=m16=c-local, row=4*qd+r=q-local
                float* ob = out + ((size_t)(b * 256 + cb + ct * 16 + m16)) * 4096
                                + q0 + qt * 16 + qd * 4;
                float4 o;
                o.x = acc[qt][ct].x * inv4.x;
                o.y = acc[qt][ct].y * inv4.y;
                o.z = acc[qt][ct].z * inv4.z;
                o.w = acc[qt][ct].w * inv4.w;
                *(float4*)ob = o;
            }
        }
    }
}

// ---------------------------------------------------------------------------
// Workspace: wq 320x256 bf16 | scale/off 320 f32 | q_t,k_t [b][n][32] bf16 |
// v_ws pair-interleaved [b][tp=32][256][16x16B]. Total ~10.7 MB.
// ---------------------------------------------------------------------------
extern "C" void kernel_launch(void* const* d_in, const int* in_sizes, int n_in,
                              void* d_out, int out_size, void* d_ws, size_t ws_size,
                              hipStream_t stream)
{
    const float* x1  = (const float*)d_in[0];
    const float* x2  = (const float*)d_in[1];
    const float* qw  = (const float*)d_in[2];
    const float* qb  = (const float*)d_in[3];
    const float* qg  = (const float*)d_in[4];
    const float* qbe = (const float*)d_in[5];
    const float* qm  = (const float*)d_in[6];
    const float* qv  = (const float*)d_in[7];
    const float* kw  = (const float*)d_in[8];
    const float* kb  = (const float*)d_in[9];
    const float* kg  = (const float*)d_in[10];
    const float* kbe = (const float*)d_in[11];
    const float* km  = (const float*)d_in[12];
    const float* kvv = (const float*)d_in[13];
    const float* vw  = (const float*)d_in[14];
    const float* vb  = (const float*)d_in[15];
    const float* vg  = (const float*)d_in[16];
    const float* vbe = (const float*)d_in[17];
    const float* vm  = (const float*)d_in[18];
    const float* vv  = (const float*)d_in[19];

    char* ws = (char*)d_ws;
    unsigned short* wq   = (unsigned short*)(ws + 0);
    float*          scale= (float*)(ws + 163840);
    float*          off  = (float*)(ws + 165120);
    unsigned short* q_t  = (unsigned short*)(ws + 166400);
    unsigned short* k_t  = (unsigned short*)(ws + 166400 + 1048576);
    unsigned short* v_ws = (unsigned short*)(ws + 166400 + 2097152);

    prep_kernel<<<320, 64, 0, stream>>>(qw, qb, qg, qbe, qm, qv,
                                        kw, kb, kg, kbe, km, kvv,
                                        vw, vb, vg, vbe, vm, vv,
                                        wq, scale, off);
    proj_kernel<<<768, 256, 0, stream>>>(x1, x2, wq, scale, off, q_t, k_t, v_ws);
    flash_kernel<<<512, 256, 0, stream>>>(q_t, k_t, v_ws, (float*)d_out);
}

// Round 10
// 177.019 us; speedup vs baseline: 2.3946x; 2.3946x over previous
//
#include <hip/hip_runtime.h>

using short8   = __attribute__((ext_vector_type(8))) short;
using f32x4    = __attribute__((ext_vector_type(4))) float;
using ushort4v = __attribute__((ext_vector_type(4))) unsigned short;

#define BN_EPS 1e-5f
// log2(e)/sqrt(32): folded into q projection so softmax uses native exp2
#define ATT_SCALE_LOG2E 0.2550348347988049f

__device__ __forceinline__ unsigned short f2bf(float f) {
    union { float f; unsigned u; } v; v.f = f;
    return (unsigned short)((v.u + 0x7FFFu + ((v.u >> 16) & 1u)) >> 16);  // RNE
}

// pack two f32 -> two bf16 (round-half-up): a in low 16, b in high 16
__device__ __forceinline__ unsigned pack2bf(float a, float b) {
    union { float f; unsigned u; } ua, ub; ua.f = a; ub.f = b;
    return __builtin_amdgcn_perm(ub.u + 0x8000u, ua.u + 0x8000u, 0x07060302u);
}

// async global->LDS, 16B per lane. gp: per-lane global src. lp: wave-uniform
// LDS base (HW adds lane*16).
__device__ __forceinline__ void glds16(const void* gp, void* lp) {
    __builtin_amdgcn_global_load_lds(
        (const __attribute__((address_space(1))) unsigned*)gp,
        (__attribute__((address_space(3))) unsigned*)lp, 16, 0, 0);
}

// ---------------------------------------------------------------------------
// Kernel 0: weights -> bf16; fold conv-bias + BN into per-row (scale, offset).
// Rows: 0-31 q, 32-63 k, 64-319 v.
// ---------------------------------------------------------------------------
__global__ void prep_kernel(
    const float* __restrict__ qw, const float* __restrict__ qb,
    const float* __restrict__ qg, const float* __restrict__ qbe,
    const float* __restrict__ qm, const float* __restrict__ qv,
    const float* __restrict__ kw, const float* __restrict__ kb,
    const float* __restrict__ kg, const float* __restrict__ kbe,
    const float* __restrict__ km, const float* __restrict__ kvv,
    const float* __restrict__ vw, const float* __restrict__ vb,
    const float* __restrict__ vg, const float* __restrict__ vbe,
    const float* __restrict__ vm, const float* __restrict__ vv,
    unsigned short* __restrict__ wq, float* __restrict__ scale,
    float* __restrict__ off)
{
    int r = blockIdx.x;      // 0..319
    int t = threadIdx.x;     // 0..63
    const float *wsrc, *g, *be, *mn, *vr, *bi;
    int rl;
    if (r < 32)      { rl = r;      wsrc = qw; g = qg; be = qbe; mn = qm; vr = qv;  bi = qb; }
    else if (r < 64) { rl = r - 32; wsrc = kw; g = kg; be = kbe; mn = km; vr = kvv; bi = kb; }
    else             { rl = r - 64; wsrc = vw; g = vg; be = vbe; mn = vm; vr = vv;  bi = vb; }

    float4 w4 = *(const float4*)(wsrc + rl * 256 + t * 4);
    ushort4v o;
    o.x = f2bf(w4.x); o.y = f2bf(w4.y); o.z = f2bf(w4.z); o.w = f2bf(w4.w);
    *(ushort4v*)(wq + r * 256 + t * 4) = o;

    if (t == 0) {
        float inv = g[rl] * rsqrtf(vr[rl] + BN_EPS);
        float ofv = bi[rl] * inv + be[rl] - mn[rl] * inv;
        float s = (r < 32) ? ATT_SCALE_LOG2E : 1.0f;
        scale[r] = inv * s;
        off[r]   = ofv * s;
    }
}

// ---------------------------------------------------------------------------
// Kernel 1: projections (r2 structure). bx>>8 = g: 0: q(x1), 1: k(x2),
// 2: v ALL 256 rows (x2). Grid 768. q_t/k_t: [b][n][32] bf16.
// v_ws: PAIR-INTERLEAVED tile-blocked layout for flash's fused-PV b128 reads:
//   [b][tp=0..31][c=0..255][16 granules x 16B], granule g (keys 4g..4g+3 of
//   the 64-key tile) = [tileA=2tp 8B | tileB=2tp+1 8B], granule slot
//   XOR-swizzled ONCE here: slot = (g&8) | ((g&7) ^ (c&7)). Flash DMAs this
//   image VERBATIM into linear LDS and applies the same swizzle on READ.
// ---------------------------------------------------------------------------
#define XT_PITCH 264

__global__ __launch_bounds__(256, 4) void proj_kernel(
    const float* __restrict__ x1, const float* __restrict__ x2,
    const unsigned short* __restrict__ wq,
    const float* __restrict__ scale, const float* __restrict__ off,
    unsigned short* __restrict__ q_t, unsigned short* __restrict__ k_t,
    unsigned short* __restrict__ v_ws)
{
    __shared__ __align__(16) unsigned short Xt[64 * XT_PITCH];   // 33792 B
    int bx = blockIdx.x;
    int g  = bx >> 8;        // 0,1,2
    int t2 = bx & 255;
    int nt = t2 & 63;
    int b  = t2 >> 6;
    int n0 = nt * 64;
    int tid = threadIdx.x;
    int wv = tid >> 6, lane = tid & 63;
    int m16 = lane & 15, qd = lane >> 4;

    const float* xb = ((g == 0) ? x1 : x2) + (size_t)b * 256 * 4096 + n0 + lane;

    // octet-gather transpose: n = lane, channels 8*o..8*o+7, o = wv*8+i
    #pragma unroll 2
    for (int i = 0; i < 8; ++i) {
        int o = wv * 8 + i;                       // 0..31
        const float* src = xb + (size_t)(o * 8) * 4096;
        uint4 dw;
        dw.x = pack2bf(src[0],                src[(size_t)1 * 4096]);
        dw.y = pack2bf(src[(size_t)2 * 4096], src[(size_t)3 * 4096]);
        dw.z = pack2bf(src[(size_t)4 * 4096], src[(size_t)5 * 4096]);
        dw.w = pack2bf(src[(size_t)6 * 4096], src[(size_t)7 * 4096]);
        *(uint4*)&Xt[lane * XT_PITCH + o * 8] = dw;
    }
    __syncthreads();

    f32x4 zero4 = {0.f, 0.f, 0.f, 0.f};

    if (g < 2) {
        int rb = g * 32;
        f32x4 acc0 = zero4, acc1 = zero4;
        #pragma unroll 2
        for (int s = 0; s < 8; ++s) {
            short8 w0 = *(const short8*)(wq + (size_t)(rb +      m16) * 256 + s * 32 + qd * 8);
            short8 w1 = *(const short8*)(wq + (size_t)(rb + 16 + m16) * 256 + s * 32 + qd * 8);
            short8 xf = *(const short8*)&Xt[(16 * wv + m16) * XT_PITCH + s * 32 + qd * 8];
            acc0 = __builtin_amdgcn_mfma_f32_16x16x32_bf16(w0, xf, acc0, 0, 0, 0);
            acc1 = __builtin_amdgcn_mfma_f32_16x16x32_bf16(w1, xf, acc1, 0, 0, 0);
        }
        unsigned short* dst = (g == 0) ? q_t : k_t;
        int ncol = n0 + 16 * wv + m16;
        #pragma unroll
        for (int tm = 0; tm < 2; ++tm) {
            f32x4 acc = tm ? acc1 : acc0;
            int r0 = 16 * tm + 4 * qd;
            float4 sc = *(const float4*)(scale + rb + r0);
            float4 of = *(const float4*)(off   + rb + r0);
            ushort4v o;
            o.x = f2bf(acc.x * sc.x + of.x);
            o.y = f2bf(acc.y * sc.y + of.y);
            o.z = f2bf(acc.z * sc.z + of.z);
            o.w = f2bf(acc.w * sc.w + of.w);
            *(ushort4v*)(dst + ((size_t)b * 4096 + ncol) * 32 + r0) = o;
        }
    } else {
        // v: all 256 rows from one x2 transpose
        f32x4 acc[4][4];
        #pragma unroll
        for (int rr = 0; rr < 4; ++rr)
            #pragma unroll
            for (int tm = 0; tm < 4; ++tm) acc[rr][tm] = zero4;
        #pragma unroll 1
        for (int s = 0; s < 8; ++s) {
            short8 xf[4];
            #pragma unroll
            for (int tm = 0; tm < 4; ++tm)
                xf[tm] = *(const short8*)&Xt[(16 * tm + m16) * XT_PITCH + s * 32 + qd * 8];
            #pragma unroll
            for (int rr = 0; rr < 4; ++rr) {
                short8 wf = *(const short8*)(wq + (size_t)(64 + rr * 64 + 16 * wv + m16) * 256 + s * 32 + qd * 8);
                #pragma unroll
                for (int tm = 0; tm < 4; ++tm)
                    acc[rr][tm] = __builtin_amdgcn_mfma_f32_16x16x32_bf16(xf[tm], wf, acc[rr][tm], 0, 0, 0);
            }
        }
        // pair-interleaved swizzled store
        unsigned short* vt = v_ws + ((size_t)b * 32 + (nt >> 1)) * 32768;
        int h = nt & 1;
        #pragma unroll
        for (int rr = 0; rr < 4; ++rr) {
            int c = rr * 64 + 16 * wv + m16;
            float sc = scale[64 + c], of = off[64 + c];
            #pragma unroll
            for (int tm = 0; tm < 4; ++tm) {
                int gg = 4 * tm + qd;                           // granule 0..15
                int gs = (gg & 8) | ((gg & 7) ^ (c & 7));       // swizzled slot
                ushort4v o;
                o.x = f2bf(acc[rr][tm].x * sc + of);
                o.y = f2bf(acc[rr][tm].y * sc + of);
                o.z = f2bf(acc[rr][tm].z * sc + of);
                o.w = f2bf(acc[rr][tm].w * sc + of);
                *(ushort4v*)(vt + c * 128 + gs * 8 + h * 4) = o;
            }
        }
    }
}

// ---------------------------------------------------------------------------
// Kernel 2: flash attention v9 — v7b + cross-epoch softmax pipeline, REGISTER-
// BUDGETED (v8 spilled: Vf[8] preload + 2nd ap set blew the 256/wave unified
// cap -> 1.38GB scratch traffic). Changes vs v8:
//   * Vf read inline in PV (1 live), B2 moved AFTER PV, prefetch after B2.
//   * exp2 in 2-qt chunks (SA/SB live 16 not 32).
//   * addr arrays -> base regs + compile-time folded offsets.
// Schedule per epoch: B1 = vmcnt(8)+barrier [DMA(ep)+K(ep+1) retired,
// DMA(ep+1) in flight]; QK(ep+1)+exp2 -> apN; PV(ep) w/ apC (setprio);
// B2 = lgkmcnt(0)+barrier [Vf reads done -> buf[ep&1] clobberable];
// issue K(ep+2) + DMA(ep+2). DMA(ep) gets ~2 epochs of flight time.
// vmcnt ledger verified: prologue 20 ops, vmcnt(18) frees KA; B1(0) frees
// KB+DMA(0); steady 18 -> vmcnt(8) frees DMA(ep)+K(ep+1); peel-31 vmcnt(0).
// ---------------------------------------------------------------------------
__global__ __launch_bounds__(256, 2) void flash_kernel(
    const unsigned short* __restrict__ q_t, const unsigned short* __restrict__ k_t,
    const unsigned short* __restrict__ v_ws, float* __restrict__ out)
{
    __shared__ __align__(16) unsigned char Vb[2][32768];   // 64 KB V pair dbuf / scratch
    __shared__ __align__(16) float Lsh[256];               // 1 KB

    int bx = blockIdx.x;                   // 512 blocks
    int cg = (bx >> 2) & 1;
    int b  = bx & 3;
    int qg = bx >> 3;                      // 0..63
    int q0 = qg * 64;
    int cb = cg * 128;

    int tid = threadIdx.x;
    int wv  = tid >> 6, lane = tid & 63;   // wv = key-slice owner
    int m16 = lane & 15, qd = lane >> 4;

    // ---- V addressing ----
    const char* vpb = (const char*)v_ws + (size_t)b * 2097152 + (size_t)cb * 256;
    const char* vsl = vpb + wv * 8192 + lane * 16;   // per-lane DMA src base
    char* vdl = (char*)Vb + wv * 8192;               // wave-uniform DMA dst base
    int gw = wv * 4 + qd;
    int gs = (gw & 8) | ((gw & 7) ^ (m16 & 7));
    int vroff = m16 * 256 + gs * 16;                 // read base; +ct*4096 folds

    // ---- K global base (wave's 16 rows, contiguous -> 1KB coalesced) ----
    const unsigned short* kbase = k_t + ((size_t)b * 4096 + wv * 16 + m16) * 32 + qd * 8;

    // ---- persistent Q fragments (all 4 q-tiles) ----
    const unsigned short* qb = q_t + ((size_t)b * 4096 + q0) * 32;
    short8 Qf[4];
    #pragma unroll
    for (int qt = 0; qt < 4; ++qt)
        Qf[qt] = *(const short8*)(qb + (size_t)(qt * 16 + m16) * 32 + qd * 8);

    f32x4 zero4 = {0.f, 0.f, 0.f, 0.f};
    f32x4 acc[4][8];
    #pragma unroll
    for (int qt = 0; qt < 4; ++qt)
        #pragma unroll
        for (int ct = 0; ct < 8; ++ct) acc[qt][ct] = zero4;
    float lsum[4] = {0.f, 0.f, 0.f, 0.f};

    // ---- prologue: K(0),K(1) first, then DMA(0),DMA(1) (20 vmem ops) ----
    short8 KA0 = *(const short8*)kbase;
    short8 KA1 = *(const short8*)(kbase + 2048);
    short8 KB0 = *(const short8*)(kbase + 4096);
    short8 KB1 = *(const short8*)(kbase + 6144);
    #pragma unroll
    for (int u = 0; u < 8; ++u) glds16(vsl + u * 1024, vdl + u * 1024);
    #pragma unroll
    for (int u = 0; u < 8; ++u) glds16(vsl + 65536 + u * 1024, vdl + 32768 + u * 1024);
    asm volatile("s_waitcnt vmcnt(18)" ::: "memory");   // KA retired

    // QK(0) + exp2 -> apA
    short8 apA[4], apB[4];
    #pragma unroll
    for (int qp = 0; qp < 2; ++qp) {
        f32x4 S0A = __builtin_amdgcn_mfma_f32_16x16x32_bf16(KA0, Qf[2 * qp],     zero4, 0, 0, 0);
        f32x4 S0B = __builtin_amdgcn_mfma_f32_16x16x32_bf16(KA1, Qf[2 * qp],     zero4, 0, 0, 0);
        f32x4 S1A = __builtin_amdgcn_mfma_f32_16x16x32_bf16(KA0, Qf[2 * qp + 1], zero4, 0, 0, 0);
        f32x4 S1B = __builtin_amdgcn_mfma_f32_16x16x32_bf16(KA1, Qf[2 * qp + 1], zero4, 0, 0, 0);
        #pragma unroll
        for (int j = 0; j < 2; ++j) {
            f32x4 SA = j ? S1A : S0A, SB = j ? S1B : S0B;
            int qt = 2 * qp + j;
            float a0 = __builtin_amdgcn_exp2f(SA.x), a1 = __builtin_amdgcn_exp2f(SA.y);
            float a2 = __builtin_amdgcn_exp2f(SA.z), a3 = __builtin_amdgcn_exp2f(SA.w);
            float b0 = __builtin_amdgcn_exp2f(SB.x), b1 = __builtin_amdgcn_exp2f(SB.y);
            float b2 = __builtin_amdgcn_exp2f(SB.z), b3 = __builtin_amdgcn_exp2f(SB.w);
            lsum[qt] += ((a0 + a1) + (a2 + a3)) + ((b0 + b1) + (b2 + b3));
            union { uint4 u; short8 s; } w;
            w.u.x = pack2bf(a0, a1); w.u.y = pack2bf(a2, a3);
            w.u.z = pack2bf(b0, b1); w.u.w = pack2bf(b2, b3);
            apA[qt] = w.s;
        }
    }

    // epoch body: PV(ep) w/ apC; QK(ep+1) w/ Ku -> apN; prefetch pair ep+2
    auto body = [&](short8 (&apC)[4], short8 (&apN)[4],
                    const short8& Ku0, const short8& Ku1,
                    short8& Kl0, short8& Kl1, int ep) {
        // B1: DMA(ep)+K(ep+1) retired; DMA(ep+1) (8 newest) in flight
        asm volatile("s_waitcnt vmcnt(8)\n\ts_barrier" ::: "memory");
        char* Vcur = (char*)Vb + (size_t)(ep & 1) * 32768;
        const char* vrb = Vcur + vroff;

        // QK(ep+1) + exp2 -> apN, 2 q-tiles at a time (SA/SB live = 16)
        #pragma unroll
        for (int qp = 0; qp < 2; ++qp) {
            f32x4 S0A = __builtin_amdgcn_mfma_f32_16x16x32_bf16(Ku0, Qf[2 * qp],     zero4, 0, 0, 0);
            f32x4 S0B = __builtin_amdgcn_mfma_f32_16x16x32_bf16(Ku1, Qf[2 * qp],     zero4, 0, 0, 0);
            f32x4 S1A = __builtin_amdgcn_mfma_f32_16x16x32_bf16(Ku0, Qf[2 * qp + 1], zero4, 0, 0, 0);
            f32x4 S1B = __builtin_amdgcn_mfma_f32_16x16x32_bf16(Ku1, Qf[2 * qp + 1], zero4, 0, 0, 0);
            #pragma unroll
            for (int j = 0; j < 2; ++j) {
                f32x4 SA = j ? S1A : S0A, SB = j ? S1B : S0B;
                int qt = 2 * qp + j;
                float a0 = __builtin_amdgcn_exp2f(SA.x), a1 = __builtin_amdgcn_exp2f(SA.y);
                float a2 = __builtin_amdgcn_exp2f(SA.z), a3 = __builtin_amdgcn_exp2f(SA.w);
                float b0 = __builtin_amdgcn_exp2f(SB.x), b1 = __builtin_amdgcn_exp2f(SB.y);
                float b2 = __builtin_amdgcn_exp2f(SB.z), b3 = __builtin_amdgcn_exp2f(SB.w);
                lsum[qt] += ((a0 + a1) + (a2 + a3)) + ((b0 + b1) + (b2 + b3));
                union { uint4 u; short8 s; } w;
                w.u.x = pack2bf(a0, a1); w.u.y = pack2bf(a2, a3);
                w.u.z = pack2bf(b0, b1); w.u.w = pack2bf(b2, b3);
                apN[qt] = w.s;
            }
        }

        // PV(ep): 32 MFMAs with PREVIOUS epoch's ap; Vf inline (1 live)
        __builtin_amdgcn_s_setprio(1);
        #pragma unroll
        for (int ct = 0; ct < 8; ++ct) {
            short8 Vf = *(const short8*)(vrb + ct * 4096);
            acc[0][ct] = __builtin_amdgcn_mfma_f32_16x16x32_bf16(apC[0], Vf, acc[0][ct], 0, 0, 0);
            acc[1][ct] = __builtin_amdgcn_mfma_f32_16x16x32_bf16(apC[1], Vf, acc[1][ct], 0, 0, 0);
            acc[2][ct] = __builtin_amdgcn_mfma_f32_16x16x32_bf16(apC[2], Vf, acc[2][ct], 0, 0, 0);
            acc[3][ct] = __builtin_amdgcn_mfma_f32_16x16x32_bf16(apC[3], Vf, acc[3][ct], 0, 0, 0);
        }
        __builtin_amdgcn_s_setprio(0);

        // B2: all waves' Vf reads retired -> buf[ep&1] clobberable
        asm volatile("s_waitcnt lgkmcnt(0)\n\ts_barrier" ::: "memory");

        if (ep < 30) {   // prefetch pair ep+2: K first, then DMA into buf[ep&1]
            const unsigned short* ks = kbase + (size_t)(ep + 2) * 4096;
            Kl0 = *(const short8*)ks;
            Kl1 = *(const short8*)(ks + 2048);
            const char* vs = vsl + (size_t)(ep + 2) * 65536;
            char* vd = vdl + (size_t)(ep & 1) * 32768;
            #pragma unroll
            for (int u = 0; u < 8; ++u) glds16(vs + u * 1024, vd + u * 1024);
        }
    };

    #pragma unroll 1
    for (int ep = 0; ep < 30; ep += 2) {
        body(apA, apB, KB0, KB1, KA0, KA1, ep);        // PV(ep),   QK(ep+1)
        body(apB, apA, KA0, KA1, KB0, KB1, ep + 1);    // PV(ep+1), QK(ep+2)
    }
    body(apA, apB, KB0, KB1, KA0, KA1, 30);            // PV(30), QK(31)->apB

    // ---- peeled epoch 31: full drain, PV only ----
    {
        asm volatile("s_waitcnt vmcnt(0)\n\ts_barrier" ::: "memory");
        const char* vrb = (char*)Vb + 32768 + vroff;
        __builtin_amdgcn_s_setprio(1);
        #pragma unroll
        for (int ct = 0; ct < 8; ++ct) {
            short8 Vf = *(const short8*)(vrb + ct * 4096);
            acc[0][ct] = __builtin_amdgcn_mfma_f32_16x16x32_bf16(apB[0], Vf, acc[0][ct], 0, 0, 0);
            acc[1][ct] = __builtin_amdgcn_mfma_f32_16x16x32_bf16(apB[1], Vf, acc[1][ct], 0, 0, 0);
            acc[2][ct] = __builtin_amdgcn_mfma_f32_16x16x32_bf16(apB[2], Vf, acc[2][ct], 0, 0, 0);
            acc[3][ct] = __builtin_amdgcn_mfma_f32_16x16x32_bf16(apB[3], Vf, acc[3][ct], 0, 0, 0);
        }
        __builtin_amdgcn_s_setprio(0);
    }

    // ---- denominators: reduce over qd in-wave; publish per key-slice ----
    #pragma unroll
    for (int qt = 0; qt < 4; ++qt) {
        float l = lsum[qt];
        l += __shfl_xor(l, 16);
        l += __shfl_xor(l, 32);
        if (lane < 16) Lsh[wv * 64 + qt * 16 + lane] = l;
    }

    // ---- O-combine over key-slices: 2-round conflict-free LDS tree ----
    char* X = (char*)Vb;   // 64 KB scratch (V bufs dead)
    asm volatile("s_waitcnt vmcnt(0) lgkmcnt(0)\n\ts_barrier" ::: "memory");
    if (wv >= 2) {
        char* dst = X + (size_t)(wv - 2) * 32768;
        #pragma unroll
        for (int qt = 0; qt < 4; ++qt)
            #pragma unroll
            for (int ct = 0; ct < 8; ++ct)
                *(f32x4*)(dst + (qt * 8 + ct) * 1024 + lane * 16) = acc[qt][ct];
    }
    asm volatile("s_waitcnt lgkmcnt(0)\n\ts_barrier" ::: "memory");
    if (wv < 2) {
        const char* src = X + (size_t)wv * 32768;
        #pragma unroll
        for (int qt = 0; qt < 4; ++qt)
            #pragma unroll
            for (int ct = 0; ct < 8; ++ct)
                acc[qt][ct] += *(const f32x4*)(src + (qt * 8 + ct) * 1024 + lane * 16);
    }
    asm volatile("s_waitcnt lgkmcnt(0)\n\ts_barrier" ::: "memory");
    if (wv == 1) {
        char* dst = X + 32768;
        #pragma unroll
        for (int qt = 0; qt < 4; ++qt)
            #pragma unroll
            for (int ct = 0; ct < 8; ++ct)
                *(f32x4*)(dst + (qt * 8 + ct) * 1024 + lane * 16) = acc[qt][ct];
    }
    asm volatile("s_waitcnt lgkmcnt(0)\n\ts_barrier" ::: "memory");
    if (wv == 0) {
        const char* src = X + 32768;
        #pragma unroll
        for (int qt = 0; qt < 4; ++qt)
            #pragma unroll
            for (int ct = 0; ct < 8; ++ct)
                acc[qt][ct] += *(const f32x4*)(src + (qt * 8 + ct) * 1024 + lane * 16);

        #pragma unroll
        for (int qt = 0; qt < 4; ++qt) {
            f32x4 s4 = *(const f32x4*)&Lsh[qt * 16 + qd * 4];
            s4 += *(const f32x4*)&Lsh[64  + qt * 16 + qd * 4];
            s4 += *(const f32x4*)&Lsh[128 + qt * 16 + qd * 4];
            s4 += *(const f32x4*)&Lsh[192 + qt * 16 + qd * 4];
            f32x4 inv4;
            inv4.x = __builtin_amdgcn_rcpf(s4.x);
            inv4.y = __builtin_amdgcn_rcpf(s4.y);
            inv4.z = __builtin_amdgcn_rcpf(s4.z);
            inv4.w = __builtin_amdgcn_rcpf(s4.w);
            #pragma unroll
            for (int ct = 0; ct < 8; ++ct) {
                // acc: col=m16=c-local, row=4*qd+r=q-local
                float* ob = out + ((size_t)(b * 256 + cb + ct * 16 + m16)) * 4096
                                + q0 + qt * 16 + qd * 4;
                float4 o;
                o.x = acc[qt][ct].x * inv4.x;
                o.y = acc[qt][ct].y * inv4.y;
                o.z = acc[qt][ct].z * inv4.z;
                o.w = acc[qt][ct].w * inv4.w;
                *(float4*)ob = o;
            }
        }
    }
}

// ---------------------------------------------------------------------------
// Workspace: wq 320x256 bf16 | scale/off 320 f32 | q_t,k_t [b][n][32] bf16 |
// v_ws pair-interleaved [b][tp=32][256][16x16B]. Total ~10.7 MB.
// ---------------------------------------------------------------------------
extern "C" void kernel_launch(void* const* d_in, const int* in_sizes, int n_in,
                              void* d_out, int out_size, void* d_ws, size_t ws_size,
                              hipStream_t stream)
{
    const float* x1  = (const float*)d_in[0];
    const float* x2  = (const float*)d_in[1];
    const float* qw  = (const float*)d_in[2];
    const float* qb  = (const float*)d_in[3];
    const float* qg  = (const float*)d_in[4];
    const float* qbe = (const float*)d_in[5];
    const float* qm  = (const float*)d_in[6];
    const float* qv  = (const float*)d_in[7];
    const float* kw  = (const float*)d_in[8];
    const float* kb  = (const float*)d_in[9];
    const float* kg  = (const float*)d_in[10];
    const float* kbe = (const float*)d_in[11];
    const float* km  = (const float*)d_in[12];
    const float* kvv = (const float*)d_in[13];
    const float* vw  = (const float*)d_in[14];
    const float* vb  = (const float*)d_in[15];
    const float* vg  = (const float*)d_in[16];
    const float* vbe = (const float*)d_in[17];
    const float* vm  = (const float*)d_in[18];
    const float* vv  = (const float*)d_in[19];

    char* ws = (char*)d_ws;
    unsigned short* wq   = (unsigned short*)(ws + 0);
    float*          scale= (float*)(ws + 163840);
    float*          off  = (float*)(ws + 165120);
    unsigned short* q_t  = (unsigned short*)(ws + 166400);
    unsigned short* k_t  = (unsigned short*)(ws + 166400 + 1048576);
    unsigned short* v_ws = (unsigned short*)(ws + 166400 + 2097152);

    prep_kernel<<<320, 64, 0, stream>>>(qw, qb, qg, qbe, qm, qv,
                                        kw, kb, kg, kbe, km, kvv,
                                        vw, vb, vg, vbe, vm, vv,
                                        wq, scale, off);
    proj_kernel<<<768, 256, 0, stream>>>(x1, x2, wq, scale, off, q_t, k_t, v_ws);
    flash_kernel<<<512, 256, 0, stream>>>(q_t, k_t, v_ws, (float*)d_out);
}